// Round 8
// baseline (32.278 us; speedup 1.0000x reference)
//
#include <hip/hip_runtime.h>

#define SEQ 2048
#define DM  2048
// B = 2. Reference einsum 'bhql,bmhn->bhqn' does NOT contract l with m:
// out[b,q,:] = ((sum_s x[b,s,:]) @ wv^T) @ wo^T, broadcast over q.
// R5: grid.sync ~100us on MI355X -> never fuse across a global dep in-kernel.
// R6: fusion is only free when redundant traffic << boundary cost (~3.5us).
//     134MB redundant L3 = +9us. This round: 16MB redundant = ~1us. OK.
// R7: 30.1us with 3 boundaries. Now: 3 dispatches / 2 boundaries.

typedef float f4 __attribute__((ext_vector_type(4)));

// ---- K1 (R1-proven): partial column sums P[b*16+y][c] = sum of 128 rows ----
__global__ __launch_bounds__(256)
void colsum_part(const float* __restrict__ x, float* __restrict__ P) {
    int c = blockIdx.x * 256 + threadIdx.x;   // 0..2047
    int y = blockIdx.y;                       // 0..15
    int b = blockIdx.z;                       // 0..1
    const float* p = x + ((size_t)b * SEQ + (size_t)y * 128) * DM + c;
    float acc = 0.f;
#pragma unroll 8
    for (int r = 0; r < 128; ++r) acc += p[(size_t)r * DM];
    P[(size_t)(b * 16 + y) * DM + c] = acc;
}

// ---- K2': fused finish-colsum + wv-matvec ----
// grid (64, 2), 512 threads. Block (nc, b): reduce the 16 partials of batch b
// into LDS (each thread = exactly one f4 column, 16 coalesced f4 loads;
// 128KB/block x 128 blocks = 16MB L3), then 8 waves x 4 rows = 32 output rows.
__global__ __launch_bounds__(512)
void red_wvmv(const float* __restrict__ P, const float* __restrict__ W,
              float* __restrict__ o) {
    int b = blockIdx.y;
    __shared__ __align__(16) float xs[DM];
    {
        const f4* Pb = (const f4*)(P + (size_t)b * 16 * DM);
        int c4 = threadIdx.x;                 // 0..511 == DM/4
        f4 a = {0.f, 0.f, 0.f, 0.f};
#pragma unroll
        for (int k = 0; k < 16; ++k) a += Pb[(size_t)k * (DM / 4) + c4];
        ((f4*)xs)[c4] = a;
    }
    __syncthreads();
    int w = threadIdx.x >> 6, lane = threadIdx.x & 63;
    const f4* xv = (const f4*)xs;
#pragma unroll
    for (int r = 0; r < 4; ++r) {
        int n = blockIdx.x * 32 + w * 4 + r;
        const f4* wr = (const f4*)(W + (size_t)n * DM);
        float a = 0.f;
#pragma unroll
        for (int i = lane; i < DM / 4; i += 64) {
            f4 aa = wr[i];
            f4 p  = xv[i];
            a += aa.x * p.x + aa.y * p.y + aa.z * p.z + aa.w * p.w;
        }
#pragma unroll
        for (int m = 32; m; m >>= 1) a += __shfl_xor(a, m, 64);
        if (lane == 0) o[b * DM + n] = a;
    }
}

// ---- K3': fused wo-matvec + broadcast, dual-batch ----
// grid (128), 512 threads. Block nc owns output cols n0..n0+15 for BOTH
// batches (one wo-row read serves both). Then writes those 16 cols for all
// 2048 q rows x 2 batches (full 64-B segments).
__global__ __launch_bounds__(512)
void wo_bcast(const float* __restrict__ v, const float* __restrict__ W,
              float* __restrict__ out) {
    int n0 = blockIdx.x * 16;
    __shared__ __align__(16) float rloc[2][16];
    int w = threadIdx.x >> 6, lane = threadIdx.x & 63;
    const f4* v0 = (const f4*)v;
    const f4* v1 = (const f4*)(v + DM);
#pragma unroll
    for (int r = 0; r < 2; ++r) {             // wave w -> rows n0+2w, n0+2w+1
        int n = n0 + w * 2 + r;
        const f4* wr = (const f4*)(W + (size_t)n * DM);
        float a0 = 0.f, a1 = 0.f;
#pragma unroll
        for (int i = lane; i < DM / 4; i += 64) {
            f4 aa = wr[i];
            f4 p  = v0[i];
            f4 q  = v1[i];
            a0 += aa.x * p.x + aa.y * p.y + aa.z * p.z + aa.w * p.w;
            a1 += aa.x * q.x + aa.y * q.y + aa.z * q.z + aa.w * q.w;
        }
#pragma unroll
        for (int m = 32; m; m >>= 1) { a0 += __shfl_xor(a0, m, 64); a1 += __shfl_xor(a1, m, 64); }
        if (lane == 0) { rloc[0][w * 2 + r] = a0; rloc[1][w * 2 + r] = a1; }
    }
    __syncthreads();
    f4 val0 = ((const f4*)rloc[0])[threadIdx.x & 3];
    f4 val1 = ((const f4*)rloc[1])[threadIdx.x & 3];
    float* o0 = out + n0;
    float* o1 = out + (size_t)SEQ * DM + n0;
    int qb = threadIdx.x >> 2;                // 0..127
#pragma unroll
    for (int it = 0; it < 16; ++it) {
        int q = qb + it * 128;                // covers 0..2047
        ((f4*)(o0 + (size_t)q * DM))[threadIdx.x & 3] = val0;
        ((f4*)(o1 + (size_t)q * DM))[threadIdx.x & 3] = val1;
    }
}

extern "C" void kernel_launch(void* const* d_in, const int* in_sizes, int n_in,
                              void* d_out, int out_size, void* d_ws, size_t ws_size,
                              hipStream_t stream) {
    const float* x  = (const float*)d_in[0];
    const float* wv = (const float*)d_in[3];
    const float* wo = (const float*)d_in[4];
    float* out = (float*)d_out;

    float* ws = (float*)d_ws;
    float* P  = ws;                  // 32 * 2048 floats = 256 KB
    float* sv = P + 32 * DM;         // 2 * 2048

    colsum_part<<<dim3(8, 16, 2), 256, 0, stream>>>(x, P);
    red_wvmv   <<<dim3(64, 2),    512, 0, stream>>>(P, wv, sv);
    wo_bcast   <<<dim3(128),      512, 0, stream>>>(sv, wo, out);
}

// Round 9
// 29.867 us; speedup vs baseline: 1.0807x; 1.0807x over previous
//
#include <hip/hip_runtime.h>

#define SEQ 2048
#define DM  2048
// B = 2. Reference einsum 'bhql,bmhn->bhqn' does NOT contract l with m:
// out[b,q,:] = ((sum_s x[b,s,:]) @ wv^T) @ wo^T, broadcast over q.
// R5: grid.sync ~100us on MI355X -> never fuse across a global dep in-kernel.
// R6: fusion only if redundant traffic-cost << boundary cost (~3.5us).
// R8: fusion must also PRESERVE full-machine parallelism (128-block kernels
//     halved the write/matvec throughput: +5.7us). This round: middle fusion
//     at 256 blocks (1/CU), K1 and K4 byte-identical to proven R7.

typedef float f4 __attribute__((ext_vector_type(4)));

// ---- K1 (R7-proven): partial column sums P[b*16+y][c] = sum of 128 rows ----
__global__ __launch_bounds__(256)
void colsum_part(const float* __restrict__ x, float* __restrict__ P) {
    int c = blockIdx.x * 256 + threadIdx.x;   // 0..2047
    int y = blockIdx.y;                       // 0..15
    int b = blockIdx.z;                       // 0..1
    const float* p = x + ((size_t)b * SEQ + (size_t)y * 128) * DM + c;
    float acc = 0.f;
#pragma unroll 8
    for (int r = 0; r < 128; ++r) acc += p[(size_t)r * DM];
    P[(size_t)(b * 16 + y) * DM + c] = acc;
}

// ---- K2 (new shape): fused finish-colsum + wv-matvec ----
// grid (128, 2) = 256 blocks (1/CU), 256 threads. Block reduces the 16
// partials of batch b into LDS (128KB L3-resident; 33.5MB aggregate ~2.2us),
// then 4 waves x 4 rows = 16 wv output rows (same rows/wave as proven K3).
__global__ __launch_bounds__(256)
void red_wvmv(const float* __restrict__ P, const float* __restrict__ W,
              float* __restrict__ o) {
    int b = blockIdx.y;
    __shared__ __align__(16) float xs[DM];
    const f4* Pb = (const f4*)(P + (size_t)b * 16 * DM);
#pragma unroll
    for (int t = 0; t < 2; ++t) {             // 512 f4-cols over 256 threads
        int c4 = threadIdx.x + t * 256;
        f4 a = {0.f, 0.f, 0.f, 0.f};
#pragma unroll
        for (int k = 0; k < 16; ++k) a += Pb[(size_t)k * (DM / 4) + c4];
        ((f4*)xs)[c4] = a;
    }
    __syncthreads();
    int w = threadIdx.x >> 6, lane = threadIdx.x & 63;
    const f4* xv = (const f4*)xs;
#pragma unroll
    for (int r = 0; r < 4; ++r) {
        int n = blockIdx.x * 16 + w * 4 + r;  // 16 rows/block
        const f4* wr = (const f4*)(W + (size_t)n * DM);
        float a = 0.f;
#pragma unroll
        for (int i = lane; i < DM / 4; i += 64) {
            f4 aa = wr[i];
            f4 p  = xv[i];
            a += aa.x * p.x + aa.y * p.y + aa.z * p.z + aa.w * p.w;
        }
#pragma unroll
        for (int m = 32; m; m >>= 1) a += __shfl_xor(a, m, 64);
        if (lane == 0) o[b * DM + n] = a;
    }
}

// ---- K3 (R7-proven K4): fused wo-matvec + broadcast ----
// grid (128, 2) = 256 blocks, 512 threads. Block (nc,b) owns output cols
// n0..n0+15 of batch b: 8 waves compute the 16 dots, then write those 16
// cols for all 2048 q rows (64-B segments).
__global__ __launch_bounds__(512)
void matvec_bcast(const float* __restrict__ v, const float* __restrict__ W,
                  float* __restrict__ out) {
    int b  = blockIdx.y;
    int n0 = blockIdx.x * 16;
    __shared__ __align__(16) float rloc[16];
    int w = threadIdx.x >> 6, lane = threadIdx.x & 63;
    const f4* vr = (const f4*)(v + (size_t)b * DM);
#pragma unroll
    for (int r = 0; r < 2; ++r) {             // wave w -> rows n0+2w, n0+2w+1
        int n = n0 + w * 2 + r;
        const f4* wr = (const f4*)(W + (size_t)n * DM);
        float a = 0.f;
#pragma unroll
        for (int i = lane; i < DM / 4; i += 64) {
            f4 aa = wr[i];
            f4 p  = vr[i];
            a += aa.x * p.x + aa.y * p.y + aa.z * p.z + aa.w * p.w;
        }
#pragma unroll
        for (int m = 32; m; m >>= 1) a += __shfl_xor(a, m, 64);
        if (lane == 0) rloc[w * 2 + r] = a;
    }
    __syncthreads();
    f4 val = ((const f4*)rloc)[threadIdx.x & 3];      // 4 threads share a row
    float* ob = out + (size_t)b * SEQ * DM + n0;
    int qb = threadIdx.x >> 2;                        // 0..127
#pragma unroll
    for (int it = 0; it < 16; ++it) {
        int q = qb + it * 128;                        // covers 0..2047
        ((f4*)(ob + (size_t)q * DM))[threadIdx.x & 3] = val;
    }
}

extern "C" void kernel_launch(void* const* d_in, const int* in_sizes, int n_in,
                              void* d_out, int out_size, void* d_ws, size_t ws_size,
                              hipStream_t stream) {
    const float* x  = (const float*)d_in[0];
    const float* wv = (const float*)d_in[3];
    const float* wo = (const float*)d_in[4];
    float* out = (float*)d_out;

    float* ws = (float*)d_ws;
    float* P  = ws;                  // 32 * 2048 floats = 256 KB
    float* sv = P + 32 * DM;         // 2 * 2048

    colsum_part <<<dim3(8, 16, 2), 256, 0, stream>>>(x, P);
    red_wvmv    <<<dim3(128, 2),   256, 0, stream>>>(P, wv, sv);
    matvec_bcast<<<dim3(128, 2),   512, 0, stream>>>(sv, wo, out);
}